// Round 7
// baseline (34.458 us; speedup 1.0000x reference)
//
#include <hip/hip_runtime.h>
#include <math.h>

#define NTH 256

__device__ __forceinline__ float frcp(float x) { return __builtin_amdgcn_rcpf(x); }
// reciprocal with sign-preserving epsilon: avoids Inf/NaN on degenerate edges
// (mirrors the reference's +EPS denominator; sign kept so t stays bounded)
__device__ __forceinline__ float frcp_eps(float d) {
    float es = __int_as_float((__float_as_int(d) & 0x80000000) | 0x322BCC77); // copysign(1e-8f,d)
    return __builtin_amdgcn_rcpf(d + es);
}

// LDS: staging only (14336 B, reused by the block reduction).
// Polygon clipping is fully register-resident: slab clipping emits <=2
// vertices per input edge (two crossings XOR crossing+endpoint), so 8 fixed
// slots + an 8-bit valid mask suffice -> no dynamic indexing anywhere.
// __launch_bounds__(256,8): 8 waves/SIMD (VGPR cap 64) — latency-bound kernel,
// occupancy is the lever (R6's (,6) cost exactly the 8/6 ratio).

__global__ __launch_bounds__(NTH, 8) void giou_kernel(
    const float* __restrict__ box, const float* __restrict__ tbox,
    double* __restrict__ wsum, int N)
{
    __shared__ float lsf[2 * 7 * NTH];   // 14336 B
    const int tid = threadIdx.x;
    const int gid = blockIdx.x * NTH + tid;

    // ---- coalesced staging: global float4 -> LDS (linear) ----
    {
        const float4* g1 = (const float4*)box;
        const float4* g2 = (const float4*)tbox;
        float4* l4 = (float4*)lsf;
        int base4 = blockIdx.x * 448;          // 448 float4 per buffer per block
        int tot4 = (N * 7) >> 2;               // N*7 divisible by 4 here (7M)
        int i0 = base4 + tid;
        if (i0 < tot4) {
            l4[tid]       = g1[i0];
            l4[448 + tid] = g2[i0];
        }
        int i1 = base4 + 256 + tid;
        if (tid < 192 && i1 < tot4) {
            l4[256 + tid]       = g1[i1];
            l4[448 + 256 + tid] = g2[i1];
        }
    }
    __syncthreads();

    float loss = 0.0f;
    if (gid < N) {
        // dword-stride 7 reads: bank = (7*tid+f)%32, gcd(7,32)=1 -> 2-way (free)
        const float* m1 = lsf + 7 * tid;
        const float* m2 = lsf + 7 * NTH + 7 * tid;
        float cx1 = m1[0], cy1 = m1[1];
        float w1 = __expf(m1[3]), l1 = __expf(m1[4]);
        float yaw1 = m1[6];
        float cx2 = m2[0], cy2 = m2[1];
        float w2 = __expf(m2[3]), l2 = __expf(m2[4]);
        float yaw2 = m2[6];

        float area1 = w1 * l1, area2 = w2 * l2;      // free w/l early
        float s1 = __sinf(yaw1), c1 = __cosf(yaw1);
        float s2 = __sinf(yaw2), c2 = __cosf(yaw2);
        float hx1 = 0.5f * w1, hy1 = 0.5f * l1;
        float hx2 = 0.5f * w2, hy2 = 0.5f * l2;

        // world-frame enclosing bbox -> enc immediately (1 live reg, not 4)
        float e1x = fmaf(hx1, fabsf(c1), hy1 * fabsf(s1));
        float e1y = fmaf(hx1, fabsf(s1), hy1 * fabsf(c1));
        float e2x = fmaf(hx2, fabsf(c2), hy2 * fabsf(s2));
        float e2y = fmaf(hx2, fabsf(s2), hy2 * fabsf(c2));
        float enc;
        {
            float xmin = fminf(cx1 - e1x, cx2 - e2x);
            float xmax = fmaxf(cx1 + e1x, cx2 + e2x);
            float ymin = fminf(cy1 - e1y, cy2 - e2y);
            float ymax = fmaxf(cy1 + e1y, cy2 + e2y);
            enc = (xmax - xmin) * (ymax - ymin);
        }

        // ---- transform quad1 into box2's frame (box2 -> axis-aligned) ----
        float sr = s1 * c2 - c1 * s2;       // sin(yaw1-yaw2)
        float cr = c1 * c2 + s1 * s2;       // cos(yaw1-yaw2)
        float tx = cx1 - cx2, ty = cy1 - cy2;
        float dxc =  c2 * tx + s2 * ty;     // R(-yaw2)*(c1-c2)
        float dyc = -s2 * tx + c2 * ty;
        float ux = hx1 * cr, uy = hx1 * sr;
        float vx = -hy1 * sr, vy = hy1 * cr;

        // CCW corners: d-u-v, d+u-v, d+u+v, d-u+v (matches ref order)
        float qx[4], qy[4];
        qx[0] = dxc - ux - vx;  qy[0] = dyc - uy - vy;
        qx[1] = dxc + ux - vx;  qy[1] = dyc + uy - vy;
        qx[2] = dxc + ux + vx;  qy[2] = dyc + uy + vy;
        qx[3] = dxc - ux + vx;  qy[3] = dyc - uy + vy;

        // ---- stage 1: y-slab |y|<=hy2 -> 8 fixed register slots + bitmask ----
        float sxv[8], syv[8];
        unsigned vmask = 0;
        float lastx = qx[3], lasty = qy[3];
        {
            float pvx = qx[3], pvy = qy[3];
            bool pB = pvy >= -hy2, pT = pvy <= hy2;
#pragma unroll
            for (int i = 0; i < 4; ++i) {
                float cxv = qx[i], cyv = qy[i];
                bool cB = cyv >= -hy2, cT = cyv <= hy2;
                float dx = cxv - pvx, dy = cyv - pvy;
                float rd = frcp_eps(dy);
                float xB = fmaf((pvy + hy2) * (-rd), dx, pvx);  // crossing y=-hy2
                float xT = fmaf((hy2 - pvy) * rd, dx, pvx);     // crossing y=+hy2
                bool crB = pB != cB;
                bool crT = pT != cT;
                bool sw  = dy < 0.0f;            // moving down: top crossed first
                float Ax = sw ? xT : xB,  Ay = sw ?  hy2 : -hy2;
                float Bx = sw ? xB : xT,  By = sw ? -hy2 :  hy2;
                bool fA = sw ? crT : crB;
                bool fB = sw ? crB : crT;
                bool ins = cB && cT;
                bool anyc = fA || fB;
                bool two  = fA && fB;            // two => !ins (far plane outside)
                bool v0 = anyc || ins;
                float s0x = anyc ? (fA ? Ax : Bx) : cxv;
                float s0y = anyc ? (fA ? Ay : By) : cyv;
                bool v1 = two || (anyc && ins);
                float s1x = two ? Bx : cxv;
                float s1y = two ? By : cyv;
                sxv[2*i]   = s0x;  syv[2*i]   = s0y;
                sxv[2*i+1] = s1x;  syv[2*i+1] = s1y;
                vmask |= (v0 ? 1u : 0u) << (2*i);
                vmask |= (v1 ? 1u : 0u) << (2*i+1);
                lastx = v1 ? s1x : (v0 ? s0x : lastx);
                lasty = v1 ? s1y : (v0 ? s0y : lasty);
                pvx = cxv; pvy = cyv; pB = cB; pT = cT;
            }
        }
        if (__popc(vmask) < 3) vmask = 0;  // == ref per-stage discard (monotone)

        // ---- stage 2: x-slab |x|<=hx2 over the 8 slots, fused shoelace ----
        float inter = 0.0f;
        {
            float pvx = lastx, pvy = lasty;     // wrap prev = last emitted
            bool pL = pvx >= -hx2, pR = pvx <= hx2;
            int j = 0;
            float fx = 0.f, fy = 0.f, px = 0.f, py = 0.f, acc = 0.f;
#pragma unroll
            for (int i = 0; i < 8; ++i) {
                bool val = (vmask >> i) & 1u;
                float cxv = sxv[i], cyv = syv[i];
                bool cL = cxv >= -hx2, cR = cxv <= hx2;
                float dx = cxv - pvx, dy = cyv - pvy;
                float rd = frcp_eps(dx);
                float yL = fmaf((pvx + hx2) * (-rd), dy, pvy);
                float yR = fmaf((hx2 - pvx) * rd, dy, pvy);
                bool crL = val && (pL != cL);
                bool crR = val && (pR != cR);
                bool sw  = dx < 0.0f;           // moving left: right plane first
                float Ax = sw ?  hx2 : -hx2, Ay = sw ? yR : yL;
                float Bx = sw ? -hx2 :  hx2, By = sw ? yL : yR;
                bool fA = sw ? crR : crL;
                bool fB = sw ? crL : crR;
                bool ins = val && cL && cR;
                {   // emit A
                    float na = fmaf(px, Ay, -(py * Ax)) + acc;
                    acc = (fA && j > 0) ? na : acc;
                    bool s0 = fA && (j == 0);
                    fx = s0 ? Ax : fx;  fy = s0 ? Ay : fy;
                    px = fA ? Ax : px;  py = fA ? Ay : py;
                    j += fA;
                }
                {   // emit B
                    float na = fmaf(px, By, -(py * Bx)) + acc;
                    acc = (fB && j > 0) ? na : acc;
                    bool s0 = fB && (j == 0);
                    fx = s0 ? Bx : fx;  fy = s0 ? By : fy;
                    px = fB ? Bx : px;  py = fB ? By : py;
                    j += fB;
                }
                {   // emit C (inside endpoint)
                    float na = fmaf(px, cyv, -(py * cxv)) + acc;
                    acc = (ins && j > 0) ? na : acc;
                    bool s0 = ins && (j == 0);
                    fx = s0 ? cxv : fx;  fy = s0 ? cyv : fy;
                    px = ins ? cxv : px;  py = ins ? cyv : py;
                    j += ins;
                }
                pvx = val ? cxv : pvx;  pvy = val ? cyv : pvy;
                pL = val ? cL : pL;     pR = val ? cR : pR;
            }
            if (j >= 3) {
                acc += fmaf(px, fy, -(py * fx));   // wrap term
                inter = fabsf(acc * 0.5f);
            }
        }

        // ---- giou ----
        float uni = area1 + area2 - inter;
        float giou = inter * frcp(uni + 1e-8f) - (enc - uni) * frcp(enc + 1e-8f);
        loss = 1.0f - giou;
    }

    // ---- reduction: f32 wave shuffle -> f64 block partial -> spread atomics ----
    float wsf = loss;
#pragma unroll
    for (int o = 32; o > 0; o >>= 1) wsf += __shfl_down(wsf, o, 64);

    __syncthreads();                      // all staging reads done
    double* red = (double*)lsf;           // reuse staging LDS for wave partials
    if ((tid & 63) == 0) red[tid >> 6] = (double)wsf;
    __syncthreads();
    if (tid == 0)
        atomicAdd(&wsum[blockIdx.x & 63], red[0] + red[1] + red[2] + red[3]);
}

__global__ void finalize_kernel(const double* __restrict__ ws,
                                const int* __restrict__ avgp,
                                float* __restrict__ out) {
    int t = threadIdx.x;
    double v = ws[t];
#pragma unroll
    for (int o = 32; o > 0; o >>= 1) v += __shfl_down(v, o, 64);
    if (t == 0) {
        int ib = *avgp;
        float fb = __int_as_float(ib);
        float av;
        if (ib > 0 && fabsf(fb) < 1e-20f) av = (float)ib;   // int32 payload
        else av = fb;                                        // f32 payload fallback
        if (!(av >= 1.0f)) av = 1.0f;
        out[0] = (float)(v / (double)av);
    }
}

extern "C" void kernel_launch(void* const* d_in, const int* in_sizes, int n_in,
                              void* d_out, int out_size, void* d_ws, size_t ws_size,
                              hipStream_t stream) {
    const float* box  = (const float*)d_in[0];
    const float* tbox = (const float*)d_in[1];
    const int*   avgp = (const int*)d_in[2];
    int N = in_sizes[0] / 7;
    double* ws = (double*)d_ws;

    hipMemsetAsync(ws, 0, 64 * sizeof(double), stream);
    int blocks = (N + NTH - 1) / NTH;
    giou_kernel<<<blocks, NTH, 0, stream>>>(box, tbox, ws, N);
    finalize_kernel<<<1, 64, 0, stream>>>(ws, avgp, (float*)d_out);
}

// Round 8
// 31.131 us; speedup vs baseline: 1.1069x; 1.1069x over previous
//
#include <hip/hip_runtime.h>
#include <math.h>

#define NTH 256

__device__ __forceinline__ float frcp(float x) { return __builtin_amdgcn_rcpf(x); }
// reciprocal with sign-preserving epsilon: avoids Inf/NaN on degenerate edges
// (mirrors the reference's +EPS denominator; sign kept so t stays bounded)
__device__ __forceinline__ float frcp_eps(float d) {
    float es = __int_as_float((__float_as_int(d) & 0x80000000) | 0x322BCC77); // copysign(1e-8f,d)
    return __builtin_amdgcn_rcpf(d + es);
}

// R5 structure (best known: 29.1us) + ONE change: coalesced float4 staging of
// box data through the SAME sp LDS buffer (14336B staging fits in the 18432B
// polygon buffer; no extra LDS, occupancy unchanged at 8 blocks/CU).
// LDS polygon buffer: rows 0..7 = vertices, row 8 = drop sink. Bank for
// [v][tid] is (2*tid)%32 independent of v -> conflict-free under divergent
// dynamic row indices.

__global__ __launch_bounds__(NTH, 8) void giou_kernel(
    const float* __restrict__ box, const float* __restrict__ tbox,
    double* __restrict__ wsum, int N)
{
    __shared__ float2 sp[9][NTH];        // 18432 B; first 14336 B double as staging
    const int tid = threadIdx.x;
    const int gid = blockIdx.x * NTH + tid;

    // ---- coalesced staging: global float4 -> LDS -> registers ----
    float cx1r, cy1r, lw1, ll1, yaw1;
    float cx2r, cy2r, lw2, ll2, yaw2;
    {
        float* lsf = (float*)sp;
        const float4* g1 = (const float4*)box;
        const float4* g2 = (const float4*)tbox;
        float4* l4 = (float4*)lsf;
        int base4 = blockIdx.x * 448;          // 448 float4 per buffer per block
        int tot4 = (N * 7) >> 2;               // N*7 divisible by 4 (7M)
        int i0 = base4 + tid;
        if (i0 < tot4) {
            l4[tid]       = g1[i0];
            l4[448 + tid] = g2[i0];
        }
        int i1 = base4 + 256 + tid;
        if (tid < 192 && i1 < tot4) {
            l4[256 + tid]       = g1[i1];
            l4[448 + 256 + tid] = g2[i1];
        }
        __syncthreads();
        // dword-stride 7: bank (7*tid+k)%32, gcd(7,32)=1 -> 2-way (free)
        const float* m1 = lsf + 7 * tid;
        const float* m2 = lsf + 7 * NTH + 7 * tid;
        cx1r = m1[0]; cy1r = m1[1]; lw1 = m1[3]; ll1 = m1[4]; yaw1 = m1[6];
        cx2r = m2[0]; cy2r = m2[1]; lw2 = m2[3]; ll2 = m2[4]; yaw2 = m2[6];
        __syncthreads();   // staging reads complete before sp rows are reused
    }

    float loss = 0.0f;
    if (gid < N) {
        float cx1 = cx1r, cy1 = cy1r;
        float w1 = __expf(lw1), l1 = __expf(ll1);
        float cx2 = cx2r, cy2 = cy2r;
        float w2 = __expf(lw2), l2 = __expf(ll2);

        float s1 = __sinf(yaw1), c1 = __cosf(yaw1);
        float s2 = __sinf(yaw2), c2 = __cosf(yaw2);
        float hx1 = 0.5f * w1, hy1 = 0.5f * l1;
        float hx2 = 0.5f * w2, hy2 = 0.5f * l2;

        // world-frame enclosing bbox via exact extent identity |u|+|v|
        float e1x = fmaf(hx1, fabsf(c1), hy1 * fabsf(s1));
        float e1y = fmaf(hx1, fabsf(s1), hy1 * fabsf(c1));
        float e2x = fmaf(hx2, fabsf(c2), hy2 * fabsf(s2));
        float e2y = fmaf(hx2, fabsf(s2), hy2 * fabsf(c2));
        float xmin = fminf(cx1 - e1x, cx2 - e2x);
        float xmax = fmaxf(cx1 + e1x, cx2 + e2x);
        float ymin = fminf(cy1 - e1y, cy2 - e2y);
        float ymax = fmaxf(cy1 + e1y, cy2 + e2y);

        // ---- transform quad1 into box2's frame (box2 -> axis-aligned) ----
        float sr = s1 * c2 - c1 * s2;       // sin(yaw1-yaw2)
        float cr = c1 * c2 + s1 * s2;       // cos(yaw1-yaw2)
        float tx = cx1 - cx2, ty = cy1 - cy2;
        float dxc =  c2 * tx + s2 * ty;     // R(-yaw2)*(c1-c2)
        float dyc = -s2 * tx + c2 * ty;
        float ux = hx1 * cr, uy = hx1 * sr;
        float vx = -hy1 * sr, vy = hy1 * cr;

        // CCW corners: d-u-v, d+u-v, d+u+v, d-u+v (matches ref order)
        float qx[4], qy[4];
        qx[0] = dxc - ux - vx;  qy[0] = dyc - uy - vy;
        qx[1] = dxc + ux - vx;  qy[1] = dyc + uy - vy;
        qx[2] = dxc + ux + vx;  qy[2] = dyc + uy + vy;
        qx[3] = dxc - ux + vx;  qy[3] = dyc - uy + vy;

        // ---- stage 1: clip by y-slab |y|<=hy2 (regs -> compacted LDS) ----
        // Per edge p->c: <=2 emits (two crossings XOR inside-endpoint), so
        // total <=8, write indices <=7: no clamps needed. Crossing points get
        // exact y=+-hy2. Order of two crossings follows sign(dy).
        int m = 0;
        {
            float pvx = qx[3], pvy = qy[3];
            bool pB = pvy >= -hy2, pT = pvy <= hy2;
#pragma unroll
            for (int i = 0; i < 4; ++i) {
                float cxv = qx[i], cyv = qy[i];
                bool cB = cyv >= -hy2, cT = cyv <= hy2;
                float dx = cxv - pvx, dy = cyv - pvy;
                float rd = frcp_eps(dy);
                float tB = (pvy + hy2) * (-rd);   // ~ ref t for plane y=-hy2
                float tT = (hy2 - pvy) * rd;      // ~ ref t for plane y=+hy2
                float xB = fmaf(tB, dx, pvx);
                float xT = fmaf(tT, dx, pvx);
                bool crB = pB != cB;
                bool crT = pT != cT;
                bool sw  = dy < 0.0f;             // moving down: top crossed first
                float Ax = sw ? xT : xB,  Ay = sw ?  hy2 : -hy2;
                float Bx = sw ? xB : xT,  By = sw ? -hy2 :  hy2;
                bool fA = sw ? crT : crB;
                bool fB = sw ? crB : crT;
                bool ins = cB && cT;
                int r;
                r = fA ? m : 8;  sp[r][tid] = make_float2(Ax, Ay);   m += fA;
                r = fB ? m : 8;  sp[r][tid] = make_float2(Bx, By);   m += fB;
                r = ins ? m : 8; sp[r][tid] = make_float2(cxv, cyv); m += ins;
                pvx = cxv; pvy = cyv; pB = cB; pT = cT;
            }
        }
        int n = (m < 3) ? 0 : m;   // == ref's per-stage discard (subset monotone)
        n = (n > 6) ? 6 : n;       // geometric bound: quad ∩ slab <= 6 verts

        // ---- stage 2: clip by x-slab |x|<=hx2, fused with shoelace ----
        float inter = 0.0f;
        {
            float rx[6], ry[6];
#pragma unroll
            for (int i = 0; i < 6; ++i) { float2 v = sp[i][tid]; rx[i] = v.x; ry[i] = v.y; }
            int npv = n - 1; if (npv < 0) npv = 0;
            float2 pvv = sp[npv][tid];            // wrap prev (dynamic row, conflict-free)
            float pvx = pvv.x, pvy = pvv.y;
            bool pL = pvx >= -hx2, pR = pvx <= hx2;
            int j = 0;
            float fx = 0.f, fy = 0.f, px = 0.f, py = 0.f, acc = 0.f;
#pragma unroll
            for (int i = 0; i < 6; ++i) {
                bool val = i < n;
                float cxv = rx[i], cyv = ry[i];
                bool cL = cxv >= -hx2, cR = cxv <= hx2;
                float dx = cxv - pvx, dy = cyv - pvy;
                float rd = frcp_eps(dx);
                float tL = (pvx + hx2) * (-rd);
                float tR = (hx2 - pvx) * rd;
                float yL = fmaf(tL, dy, pvy);
                float yR = fmaf(tR, dy, pvy);
                bool crL = val && (pL != cL);
                bool crR = val && (pR != cR);
                bool sw  = dx < 0.0f;             // moving left: right plane first
                float Ax = sw ?  hx2 : -hx2, Ay = sw ? yR : yL;
                float Bx = sw ? -hx2 :  hx2, By = sw ? yL : yR;
                bool fA = sw ? crR : crL;
                bool fB = sw ? crL : crR;
                bool ins = val && cL && cR;
                {   // emit A
                    float na = fmaf(px, Ay, -(py * Ax)) + acc;
                    acc = (fA && j > 0) ? na : acc;
                    bool s0 = fA && (j == 0);
                    fx = s0 ? Ax : fx;  fy = s0 ? Ay : fy;
                    px = fA ? Ax : px;  py = fA ? Ay : py;
                    j += fA;
                }
                {   // emit B
                    float na = fmaf(px, By, -(py * Bx)) + acc;
                    acc = (fB && j > 0) ? na : acc;
                    bool s0 = fB && (j == 0);
                    fx = s0 ? Bx : fx;  fy = s0 ? By : fy;
                    px = fB ? Bx : px;  py = fB ? By : py;
                    j += fB;
                }
                {   // emit C (inside endpoint)
                    float na = fmaf(px, cyv, -(py * cxv)) + acc;
                    acc = (ins && j > 0) ? na : acc;
                    bool s0 = ins && (j == 0);
                    fx = s0 ? cxv : fx;  fy = s0 ? cyv : fy;
                    px = ins ? cxv : px;  py = ins ? cyv : py;
                    j += ins;
                }
                pvx = val ? cxv : pvx;  pvy = val ? cyv : pvy;
                pL = val ? cL : pL;     pR = val ? cR : pR;
            }
            if (j >= 3) {
                acc += fmaf(px, fy, -(py * fx));   // wrap term
                inter = fabsf(acc * 0.5f);
            }
        }

        // ---- giou (areas are rotation-invariant; bbox in world frame) ----
        float area1 = w1 * l1, area2 = w2 * l2;
        float uni = area1 + area2 - inter;
        float enc = (xmax - xmin) * (ymax - ymin);
        float giou = inter * frcp(uni + 1e-8f) - (enc - uni) * frcp(enc + 1e-8f);
        loss = 1.0f - giou;
    }

    // ---- reduction: f32 wave shuffle -> f64 block partial -> spread atomics ----
    float wsf = loss;
#pragma unroll
    for (int o = 32; o > 0; o >>= 1) wsf += __shfl_down(wsf, o, 64);

    __syncthreads();                      // done with LDS columns
    double* red = (double*)&sp[0][0];     // reuse LDS for 4 wave partials
    if ((tid & 63) == 0) red[tid >> 6] = (double)wsf;
    __syncthreads();
    if (tid == 0)
        atomicAdd(&wsum[blockIdx.x & 63], red[0] + red[1] + red[2] + red[3]);
}

__global__ void finalize_kernel(const double* __restrict__ ws,
                                const int* __restrict__ avgp,
                                float* __restrict__ out) {
    int t = threadIdx.x;
    double v = ws[t];
#pragma unroll
    for (int o = 32; o > 0; o >>= 1) v += __shfl_down(v, o, 64);
    if (t == 0) {
        int ib = *avgp;
        float fb = __int_as_float(ib);
        float av;
        if (ib > 0 && fabsf(fb) < 1e-20f) av = (float)ib;   // int32 payload
        else av = fb;                                        // f32 payload fallback
        if (!(av >= 1.0f)) av = 1.0f;
        out[0] = (float)(v / (double)av);
    }
}

extern "C" void kernel_launch(void* const* d_in, const int* in_sizes, int n_in,
                              void* d_out, int out_size, void* d_ws, size_t ws_size,
                              hipStream_t stream) {
    const float* box  = (const float*)d_in[0];
    const float* tbox = (const float*)d_in[1];
    const int*   avgp = (const int*)d_in[2];
    int N = in_sizes[0] / 7;
    double* ws = (double*)d_ws;

    hipMemsetAsync(ws, 0, 64 * sizeof(double), stream);
    int blocks = (N + NTH - 1) / NTH;
    giou_kernel<<<blocks, NTH, 0, stream>>>(box, tbox, ws, N);
    finalize_kernel<<<1, 64, 0, stream>>>(ws, avgp, (float*)d_out);
}

// Round 9
// 27.428 us; speedup vs baseline: 1.2563x; 1.1350x over previous
//
#include <hip/hip_runtime.h>
#include <math.h>

#define NTH 256

__device__ __forceinline__ float frcp(float x) { return __builtin_amdgcn_rcpf(x); }
// reciprocal with sign-preserving epsilon: bounded result on degenerate edges
// (mirrors the reference's +EPS denominator role)
__device__ __forceinline__ float frcp_eps(float d) {
    float es = __int_as_float((__float_as_int(d) & 0x80000000) | 0x322BCC77); // copysign(1e-8f,d)
    return __builtin_amdgcn_rcpf(d + es);
}

// Closed-form box-clip area via Green's theorem, A = -∮ y dx:
//  * boundary parts on x=±hx have dx=0 -> contribute 0
//  * boundary parts on y=±hy contribute hy * (clamped in-quad interval length)
//  * each quad edge contributes -dx_e*dt*(py + 0.5*dy_e*(t0+t1)) over its
//    in-box parameter interval [t0,t1] (pure clamp arithmetic)
// => fully edge-local, branch-free, no polygon storage, no serial emit chain.

__global__ __launch_bounds__(NTH, 8) void giou_kernel(
    const float* __restrict__ box, const float* __restrict__ tbox,
    double* __restrict__ wsum, int N)
{
    __shared__ double red[4];
    const int tid = threadIdx.x;
    const int gid = blockIdx.x * NTH + tid;

    float loss = 0.0f;
    if (gid < N) {
        const float* b1 = box  + (size_t)gid * 7;
        const float* b2 = tbox + (size_t)gid * 7;
        float cx1 = b1[0], cy1 = b1[1];
        float w1 = __expf(b1[3]), l1 = __expf(b1[4]);
        float yaw1 = b1[6];
        float cx2 = b2[0], cy2 = b2[1];
        float w2 = __expf(b2[3]), l2 = __expf(b2[4]);
        float yaw2 = b2[6];

        float s1 = __sinf(yaw1), c1 = __cosf(yaw1);
        float s2 = __sinf(yaw2), c2 = __cosf(yaw2);
        float hx1 = 0.5f * w1, hy1 = 0.5f * l1;
        float hx  = 0.5f * w2, hy  = 0.5f * l2;   // box2 half-extents (clip box)

        // world-frame enclosing bbox via exact extent identity |u|+|v|
        float e1x = fmaf(hx1, fabsf(c1), hy1 * fabsf(s1));
        float e1y = fmaf(hx1, fabsf(s1), hy1 * fabsf(c1));
        float e2x = fmaf(hx, fabsf(c2), hy * fabsf(s2));
        float e2y = fmaf(hx, fabsf(s2), hy * fabsf(c2));
        float enc;
        {
            float xmin = fminf(cx1 - e1x, cx2 - e2x);
            float xmax = fmaxf(cx1 + e1x, cx2 + e2x);
            float ymin = fminf(cy1 - e1y, cy2 - e2y);
            float ymax = fmaxf(cy1 + e1y, cy2 + e2y);
            enc = (xmax - xmin) * (ymax - ymin);
        }

        // ---- transform quad1 into box2's frame (box2 -> axis-aligned) ----
        float sr = s1 * c2 - c1 * s2;       // sin(yaw1-yaw2)
        float cr = c1 * c2 + s1 * s2;       // cos(yaw1-yaw2)
        float tx = cx1 - cx2, ty = cy1 - cy2;
        float dxc =  c2 * tx + s2 * ty;     // R(-yaw2)*(c1-c2)
        float dyc = -s2 * tx + c2 * ty;
        float ux = hx1 * cr, uy = hx1 * sr;
        float vx = -hy1 * sr, vy = hy1 * cr;

        // CCW corners: d-u-v, d+u-v, d+u+v, d-u+v
        float qx[4], qy[4];
        qx[0] = dxc - ux - vx;  qy[0] = dyc - uy - vy;
        qx[1] = dxc + ux - vx;  qy[1] = dyc + uy - vy;
        qx[2] = dxc + ux + vx;  qy[2] = dyc + uy + vy;
        qx[3] = dxc - ux + vx;  qy[3] = dyc - uy + vy;

        // ---- edge-local area accumulation ----
        const float INFP = __int_as_float(0x7f800000);
        float areaP = 0.0f;
        float xTmin = INFP, xTmax = -INFP;   // crossings with y=+hy
        float xBmin = INFP, xBmax = -INFP;   // crossings with y=-hy
#pragma unroll
        for (int i = 0; i < 4; ++i) {
            float px = qx[i], py = qy[i];
            float cxv = qx[(i + 1) & 3], cyv = qy[(i + 1) & 3];
            float dxe = cxv - px, dye = cyv - py;
            float rdx = frcp_eps(dxe), rdy = frcp_eps(dye);

            // parameter interval of this edge inside the box
            float ta = (-hx - px) * rdx, tb = (hx - px) * rdx;
            float txlo = fminf(ta, tb), txhi = fmaxf(ta, tb);
            float tc = (-hy - py) * rdy, td = (hy - py) * rdy;
            float tylo = fminf(tc, td), tyhi = fmaxf(tc, td);
            float t0 = fmaxf(fmaxf(txlo, tylo), 0.0f);
            float t1 = fminf(fminf(txhi, tyhi), 1.0f);
            float dt = fmaxf(t1 - t0, 0.0f);
            // -∫ y dx over [t0,t1]
            areaP -= dxe * dt * fmaf(0.5f * dye, t0 + t1, py);

            // crossings with the horizontal box lines (for correction terms)
            bool crT = (py > hy) != (cyv > hy);
            float xT = fmaf((hy - py) * rdy, dxe, px);
            xTmin = fminf(xTmin, crT ? xT : INFP);
            xTmax = fmaxf(xTmax, crT ? xT : -INFP);
            bool crB = (py > -hy) != (cyv > -hy);
            float xB = fmaf((-hy - py) * rdy, dxe, px);
            xBmin = fminf(xBmin, crB ? xB : INFP);
            xBmax = fmaxf(xBmax, crB ? xB : -INFP);
        }
        // empty-crossing case: -INF - INF = -INF -> max(0,.) = 0 (no guards)
        float Ltop = fmaxf(0.0f, fminf(xTmax, hx) - fmaxf(xTmin, -hx));
        float Lbot = fmaxf(0.0f, fminf(xBmax, hx) - fmaxf(xBmin, -hx));
        float inter = fabsf(fmaf(hy, Ltop + Lbot, areaP));

        // ---- giou (areas rotation-invariant; bbox in world frame) ----
        float area1 = w1 * l1, area2 = w2 * l2;
        float uni = area1 + area2 - inter;
        float giou = inter * frcp(uni + 1e-8f) - (enc - uni) * frcp(enc + 1e-8f);
        loss = 1.0f - giou;
    }

    // ---- reduction: f32 wave shuffle -> f64 block partial -> spread atomics ----
    float wsf = loss;
#pragma unroll
    for (int o = 32; o > 0; o >>= 1) wsf += __shfl_down(wsf, o, 64);

    if ((tid & 63) == 0) red[tid >> 6] = (double)wsf;
    __syncthreads();
    if (tid == 0)
        atomicAdd(&wsum[blockIdx.x & 63], red[0] + red[1] + red[2] + red[3]);
}

__global__ void finalize_kernel(const double* __restrict__ ws,
                                const int* __restrict__ avgp,
                                float* __restrict__ out) {
    int t = threadIdx.x;
    double v = ws[t];
#pragma unroll
    for (int o = 32; o > 0; o >>= 1) v += __shfl_down(v, o, 64);
    if (t == 0) {
        int ib = *avgp;
        float fb = __int_as_float(ib);
        float av;
        if (ib > 0 && fabsf(fb) < 1e-20f) av = (float)ib;   // int32 payload
        else av = fb;                                        // f32 payload fallback
        if (!(av >= 1.0f)) av = 1.0f;
        out[0] = (float)(v / (double)av);
    }
}

extern "C" void kernel_launch(void* const* d_in, const int* in_sizes, int n_in,
                              void* d_out, int out_size, void* d_ws, size_t ws_size,
                              hipStream_t stream) {
    const float* box  = (const float*)d_in[0];
    const float* tbox = (const float*)d_in[1];
    const int*   avgp = (const int*)d_in[2];
    int N = in_sizes[0] / 7;
    double* ws = (double*)d_ws;

    hipMemsetAsync(ws, 0, 64 * sizeof(double), stream);
    int blocks = (N + NTH - 1) / NTH;
    giou_kernel<<<blocks, NTH, 0, stream>>>(box, tbox, ws, N);
    finalize_kernel<<<1, 64, 0, stream>>>(ws, avgp, (float*)d_out);
}

// Round 10
// 21.069 us; speedup vs baseline: 1.6355x; 1.3018x over previous
//
#include <hip/hip_runtime.h>
#include <math.h>

#define NTH 256

__device__ __forceinline__ float frcp(float x) { return __builtin_amdgcn_rcpf(x); }
// reciprocal with sign-preserving epsilon: bounded result on degenerate edges
// (mirrors the reference's +EPS denominator role). Note frcp_eps(-d) == -frcp_eps(d).
__device__ __forceinline__ float frcp_eps(float d) {
    float es = __int_as_float((__float_as_int(d) & 0x80000000) | 0x322BCC77); // copysign(1e-8f,d)
    return __builtin_amdgcn_rcpf(d + es);
}

// Closed-form box-clip area via Green's theorem, A = -∮ y dx (see R9).
// Edge symmetry: CCW edge vectors are +2u, +2v, -2u, -2v -> only 4 rcp needed,
// negations fold into FMA input modifiers.

__global__ __launch_bounds__(NTH, 8) void giou_kernel(
    const float* __restrict__ box, const float* __restrict__ tbox,
    double* __restrict__ wsum, int N)
{
    __shared__ double red[4];
    const int tid = threadIdx.x;
    const int gid = blockIdx.x * NTH + tid;

    float loss = 0.0f;
    if (gid < N) {
        const float* b1 = box  + (size_t)gid * 7;
        const float* b2 = tbox + (size_t)gid * 7;
        float cx1 = b1[0], cy1 = b1[1];
        float w1 = __expf(b1[3]), l1 = __expf(b1[4]);
        float yaw1 = b1[6];
        float cx2 = b2[0], cy2 = b2[1];
        float w2 = __expf(b2[3]), l2 = __expf(b2[4]);
        float yaw2 = b2[6];

        float s1 = __sinf(yaw1), c1 = __cosf(yaw1);
        float s2 = __sinf(yaw2), c2 = __cosf(yaw2);
        float hx1 = 0.5f * w1, hy1 = 0.5f * l1;
        float hx  = 0.5f * w2, hy  = 0.5f * l2;   // box2 half-extents (clip box)

        // world-frame enclosing bbox via exact extent identity |u|+|v|
        float e1x = fmaf(hx1, fabsf(c1), hy1 * fabsf(s1));
        float e1y = fmaf(hx1, fabsf(s1), hy1 * fabsf(c1));
        float e2x = fmaf(hx, fabsf(c2), hy * fabsf(s2));
        float e2y = fmaf(hx, fabsf(s2), hy * fabsf(c2));
        float enc;
        {
            float xmin = fminf(cx1 - e1x, cx2 - e2x);
            float xmax = fmaxf(cx1 + e1x, cx2 + e2x);
            float ymin = fminf(cy1 - e1y, cy2 - e2y);
            float ymax = fmaxf(cy1 + e1y, cy2 + e2y);
            enc = (xmax - xmin) * (ymax - ymin);
        }

        // ---- transform quad1 into box2's frame (box2 -> axis-aligned) ----
        float sr = s1 * c2 - c1 * s2;       // sin(yaw1-yaw2)
        float cr = c1 * c2 + s1 * s2;       // cos(yaw1-yaw2)
        float tx = cx1 - cx2, ty = cy1 - cy2;
        float dxc =  c2 * tx + s2 * ty;     // R(-yaw2)*(c1-c2)
        float dyc = -s2 * tx + c2 * ty;
        float ux = hx1 * cr, uy = hx1 * sr;
        float vx = -hy1 * sr, vy = hy1 * cr;

        // CCW corners: d-u-v, d+u-v, d+u+v, d-u+v
        float qx[4], qy[4];
        qx[0] = dxc - ux - vx;  qy[0] = dyc - uy - vy;
        qx[1] = dxc + ux - vx;  qy[1] = dyc + uy - vy;
        qx[2] = dxc + ux + vx;  qy[2] = dyc + uy + vy;
        qx[3] = dxc - ux + vx;  qy[3] = dyc - uy + vy;

        // edge vectors (exact): e0=+2u e1=+2v e2=-2u e3=-2v; 4 shared rcps
        float Ux = 2.0f * ux, Uy = 2.0f * uy;
        float Vx = 2.0f * vx, Vy = 2.0f * vy;
        float rUx = frcp_eps(Ux), rUy = frcp_eps(Uy);
        float rVx = frcp_eps(Vx), rVy = frcp_eps(Vy);

        // hoisted per-vertex threshold compares (shared by adjacent edges)
        bool gT[4], gB[4];
#pragma unroll
        for (int k = 0; k < 4; ++k) { gT[k] = qy[k] > hy; gB[k] = qy[k] > -hy; }

        const float INFP = __int_as_float(0x7f800000);
        float areaP = 0.0f;
        float xTmin = INFP, xTmax = -INFP;   // crossings with y=+hy
        float xBmin = INFP, xBmax = -INFP;   // crossings with y=-hy
#pragma unroll
        for (int i = 0; i < 4; ++i) {
            float px = qx[i], py = qy[i];
            int ip1 = (i + 1) & 3;
            // edge direction and shared reciprocals (negation = input modifier)
            float dxe = (i == 0) ? Ux : (i == 1) ? Vx : (i == 2) ? -Ux : -Vx;
            float dye = (i == 0) ? Uy : (i == 1) ? Vy : (i == 2) ? -Uy : -Vy;
            float rdx = (i == 0) ? rUx : (i == 1) ? rVx : (i == 2) ? -rUx : -rVx;
            float rdy = (i == 0) ? rUy : (i == 1) ? rVy : (i == 2) ? -rUy : -rVy;

            // parameter interval of this edge inside the box
            float ta = (-hx - px) * rdx, tb = (hx - px) * rdx;
            float txlo = fminf(ta, tb), txhi = fmaxf(ta, tb);
            float tc = (-hy - py) * rdy, td = (hy - py) * rdy;
            float tylo = fminf(tc, td), tyhi = fmaxf(tc, td);
            float t0 = fmaxf(fmaxf(txlo, tylo), 0.0f);
            float t1 = fminf(fminf(txhi, tyhi), 1.0f);
            float dt = fmaxf(t1 - t0, 0.0f);
            // -∫ y dx over [t0,t1]
            areaP -= dxe * dt * fmaf(0.5f * dye, t0 + t1, py);

            // crossings with the horizontal box lines (for correction terms)
            bool crT = gT[i] != gT[ip1];
            float xT = fmaf(td, dxe, px);            // td == (hy-py)*rdy
            xTmin = fminf(xTmin, crT ? xT : INFP);
            xTmax = fmaxf(xTmax, crT ? xT : -INFP);
            bool crB = gB[i] != gB[ip1];
            float xB = fmaf(tc, dxe, px);            // tc == (-hy-py)*rdy
            xBmin = fminf(xBmin, crB ? xB : INFP);
            xBmax = fmaxf(xBmax, crB ? xB : -INFP);
        }
        // empty-crossing case: -INF - INF = -INF -> max(0,.) = 0 (no guards)
        float Ltop = fmaxf(0.0f, fminf(xTmax, hx) - fmaxf(xTmin, -hx));
        float Lbot = fmaxf(0.0f, fminf(xBmax, hx) - fmaxf(xBmin, -hx));
        float inter = fabsf(fmaf(hy, Ltop + Lbot, areaP));

        // ---- giou (areas rotation-invariant; bbox in world frame) ----
        float area1 = w1 * l1, area2 = w2 * l2;
        float uni = area1 + area2 - inter;
        float giou = inter * frcp(uni + 1e-8f) - (enc - uni) * frcp(enc + 1e-8f);
        loss = 1.0f - giou;
    }

    // ---- reduction: f32 wave shuffle -> f64 block partial -> per-block store ----
    float wsf = loss;
#pragma unroll
    for (int o = 32; o > 0; o >>= 1) wsf += __shfl_down(wsf, o, 64);

    if ((tid & 63) == 0) red[tid >> 6] = (double)wsf;
    __syncthreads();
    if (tid == 0)
        wsum[blockIdx.x] = red[0] + red[1] + red[2] + red[3];  // plain store: no memset, no atomic
}

__global__ __launch_bounds__(NTH) void finalize_kernel(
    const double* __restrict__ ws, int nblk,
    const int* __restrict__ avgp, float* __restrict__ out)
{
    __shared__ double r[NTH];
    int t = threadIdx.x;
    double v = 0.0;
    for (int i = t; i < nblk; i += NTH) v += ws[i];
    r[t] = v;
    __syncthreads();
#pragma unroll
    for (int s = NTH / 2; s > 0; s >>= 1) {
        if (t < s) r[t] += r[t + s];
        __syncthreads();
    }
    if (t == 0) {
        int ib = *avgp;
        float fb = __int_as_float(ib);
        float av;
        if (ib > 0 && fabsf(fb) < 1e-20f) av = (float)ib;   // int32 payload
        else av = fb;                                        // f32 payload fallback
        if (!(av >= 1.0f)) av = 1.0f;
        out[0] = (float)(r[0] / (double)av);
    }
}

extern "C" void kernel_launch(void* const* d_in, const int* in_sizes, int n_in,
                              void* d_out, int out_size, void* d_ws, size_t ws_size,
                              hipStream_t stream) {
    const float* box  = (const float*)d_in[0];
    const float* tbox = (const float*)d_in[1];
    const int*   avgp = (const int*)d_in[2];
    int N = in_sizes[0] / 7;
    double* ws = (double*)d_ws;

    int blocks = (N + NTH - 1) / NTH;
    giou_kernel<<<blocks, NTH, 0, stream>>>(box, tbox, ws, N);
    finalize_kernel<<<1, NTH, 0, stream>>>(ws, blocks, avgp, (float*)d_out);
}